// Round 4
// baseline (462.004 us; speedup 1.0000x reference)
//
#include <hip/hip_runtime.h>

typedef _Float16 f16;
typedef _Float16 f16x8 __attribute__((ext_vector_type(8)));
typedef float f32x16 __attribute__((ext_vector_type(16)));

#define NB 32
#define NT 512
#define ND 256
#define NH 512
#define M_REAL 16352   // NB*(NT-1)
#define RDIM 768       // ND + NH
#define TILE_ELEMS 98304  // 96 ch * 128 rows * 8 f16 per tile
#define NTN 33            // 32 real n-tiles + 1 trans tile (cols 4096..4223)

// output offsets (floats)
#define OFF_PI 0
#define OFF_S  256
#define OFF_H  1048832
#define OFF_Y  1179904
#define OFF_G1 1196288
#define OFF_G2 1327360
#define OFF_F  2373888
#define OFF_BW 2504960

// ws offsets (bytes)
#define WS_A    0            // f16 tiled [128][96][128][8] = 25165824 B
#define WS_B    25165824     // f16 tiled [33][96][128][8]  = 6488064 B
#define WS_BIAS 31653888     // f32 [4224]
#define WS_SQ   31671296     // f32 [16384][8][4] = 2097152 B
#define WS_NEED 33768448

#define CH_CONST 1887.3506062251f   // -0.5*512*(log(2pi)+log(1e-4))
#define CY_CONST 943.6753031126f    // -0.5*256*(...)
#define LOG2E 1.4426950408889634f
#define LN2 0.6931471805599453f

// conv grid layout (R12): 16-row chunks through LDS transpose
#define CA_BLOCKS 1024   // 16384/16 rows of A
#define CB_BLOCKS 264    // 4224/16 rows of B
#define EM_BASE   1288   // CA_BLOCKS + CB_BLOCKS
#define CONV_GRID 2312   // EM_BASE + 16384/16 emission blocks

__device__ __forceinline__ float fexp2(float x) { return __builtin_amdgcn_exp2f(x); }
__device__ __forceinline__ float flog2(float x) { return __builtin_amdgcn_logf(x); }
__device__ __forceinline__ float ftanh(float x) {
    x = fminf(10.f, fmaxf(-10.f, x));
    float t = fexp2(x * 2.885390081777927f);  // 2*log2(e)
    return (t - 1.f) * __builtin_amdgcn_rcpf(t + 1.f);
}
// R13: pairwise-tree max AND sum — cuts the serial dependency chain in the
// scan kernel's 511-step recurrence (~32cy serial += -> ~12cy tree).
__device__ __forceinline__ float lse8v(const float* z) {
    float M = fmaxf(fmaxf(fmaxf(z[0], z[1]), fmaxf(z[2], z[3])),
                    fmaxf(fmaxf(z[4], z[5]), fmaxf(z[6], z[7])));
    const float e0 = fexp2((z[0] - M) * LOG2E), e1 = fexp2((z[1] - M) * LOG2E);
    const float e2 = fexp2((z[2] - M) * LOG2E), e3 = fexp2((z[3] - M) * LOG2E);
    const float e4 = fexp2((z[4] - M) * LOG2E), e5 = fexp2((z[5] - M) * LOG2E);
    const float e6 = fexp2((z[6] - M) * LOG2E), e7 = fexp2((z[7] - M) * LOG2E);
    const float s = ((e0 + e1) + (e2 + e3)) + ((e4 + e5) + (e6 + e7));
    return M + LN2 * flog2(s);
}

// -------- conv (A + extended B incl. Wt tile) | emission, one kernel ----------
// tiled index for (row m, col c): (m>>7)*98304 + (c>>3)*1024 + (m&127)*8 + (c&7)
// R12: conv_a/conv_b stage through a padded LDS tile so GLOBAL WRITES are
// m-fastest (256B-contiguous segments) instead of 64 scattered 16B stores at
// 2KB stride per wave. Reads keep the old coalesced ch-fastest pattern.
__global__ __launch_bounds__(256) void conv_kernel(
    const float* __restrict__ x, const float* __restrict__ h, const float* __restrict__ y,
    const float* __restrict__ Wih, const float* __restrict__ Whh,
    const float* __restrict__ bih, const float* __restrict__ bhh,
    const float* __restrict__ Wt, const float* __restrict__ btv,
    const float* __restrict__ W1, const float* __restrict__ b1,
    const float* __restrict__ W2, const float* __restrict__ b2,
    const float* __restrict__ W3, const float* __restrict__ b3, f16* __restrict__ A,
    f16* __restrict__ Bm, float* __restrict__ biasc, float* __restrict__ out) {
    __shared__ __align__(16) float smem[11904];  // emission arena / conv transpose buf
    const int tid = threadIdx.x;
    if (blockIdx.x < CA_BLOCKS) {  // -------- conv_a: 16 rows x 96 ch --------
        const int m0 = blockIdx.x * 16;
        f16x8* tb = (f16x8*)smem;  // [16][97] padded
#pragma unroll
        for (int i = 0; i < 6; ++i) {
            const int idx = tid + 256 * i;  // 0..1535
            const int ml = idx / 96;
            const int ch = idx - ml * 96;
            const int m = m0 + ml;
            f16x8 pk = (f16x8)(f16)0.f;
            if (m < M_REAL) {
                const int b = m / 511;
                const int t = m - b * 511;
                const int c0 = ch * 8;
                const float* src = (c0 < ND) ? x + (size_t)(b * NT + t + 1) * ND + c0
                                             : h + (size_t)(b * NT + t) * NH + (c0 - ND);
                const float4 u = ((const float4*)src)[0];
                const float4 v = ((const float4*)src)[1];
                pk[0] = (f16)u.x; pk[1] = (f16)u.y; pk[2] = (f16)u.z; pk[3] = (f16)u.w;
                pk[4] = (f16)v.x; pk[5] = (f16)v.y; pk[6] = (f16)v.z; pk[7] = (f16)v.w;
            }
            tb[ml * 97 + ch] = pk;
        }
        __syncthreads();
        const size_t tbase = (size_t)(m0 >> 7) * TILE_ELEMS + (size_t)(m0 & 127) * 8;
#pragma unroll
        for (int i = 0; i < 6; ++i) {
            const int idx = tid + 256 * i;
            const int ch2 = idx >> 4;
            const int m2 = idx & 15;
            *(f16x8*)(A + tbase + (size_t)ch2 * 1024 + (size_t)m2 * 8) = tb[m2 * 97 + ch2];
        }
    } else if (blockIdx.x < EM_BASE) {  // -------- conv_b: 16 rows x 96 ch ------
        const int n0 = (blockIdx.x - CA_BLOCKS) * 16;
        f16x8* tb = (f16x8*)smem;  // [16][97]
#pragma unroll
        for (int i = 0; i < 6; ++i) {
            const int idx = tid + 256 * i;
            const int nl = idx / 96;
            const int ch = idx - nl * 96;
            const int n = n0 + nl;
            const int c0 = ch * 8;
            f16x8 pk = (f16x8)(f16)0.f;
            const float* src = nullptr;
            if (n < 4096) {
                src = (c0 < ND) ? Wih + (size_t)n * ND + c0 : Whh + (size_t)n * NH + (c0 - ND);
            } else {
                const int c = n - 4096;
                if (c < 64 && c0 >= ND) src = Wt + (size_t)c * NH + (c0 - ND);
            }
            if (src) {
                const float4 u = ((const float4*)src)[0];
                const float4 v = ((const float4*)src)[1];
                pk[0] = (f16)u.x; pk[1] = (f16)u.y; pk[2] = (f16)u.z; pk[3] = (f16)u.w;
                pk[4] = (f16)v.x; pk[5] = (f16)v.y; pk[6] = (f16)v.z; pk[7] = (f16)v.w;
            }
            tb[nl * 97 + ch] = pk;
        }
        if (tid < 16) {
            const int n = n0 + tid;
            biasc[n] = (n < 4096) ? bih[n] + bhh[n] : ((n - 4096) < 64 ? btv[n - 4096] : 0.f);
        }
        __syncthreads();
        const size_t tbase = (size_t)(n0 >> 7) * TILE_ELEMS + (size_t)(n0 & 127) * 8;
#pragma unroll
        for (int i = 0; i < 6; ++i) {
            const int idx = tid + 256 * i;
            const int ch2 = idx >> 4;
            const int m2 = idx & 15;
            *(f16x8*)(Bm + tbase + (size_t)ch2 * 1024 + (size_t)m2 * 8) = tb[m2 * 97 + ch2];
        }
    } else {  // -------- emission MLP + gaussian lp --------
        float* ssh = smem;           // 16*512
        float* W2sh = smem + 8192;   // 64*33
        float* h1sh = smem + 10304;  // 16*32
        float* h2sh = smem + 10816;  // 16*64
        float* red = smem + 11840;   // 16*4
        const int wv = tid >> 6;
        const int o = tid >> 3, seg = tid & 7;
        const int p0 = (blockIdx.x - EM_BASE) * 16;
        float4 w1r[16], w3r[16];
        {
            const float4* w1p = (const float4*)(W1 + (size_t)o * NH + seg * 64);
#pragma unroll
            for (int j = 0; j < 16; ++j) w1r[j] = w1p[(j + seg * 2) & 15];  // staggered
            const float4* w3p = (const float4*)(W3 + (size_t)tid * 64);
#pragma unroll
            for (int j = 0; j < 16; ++j) w3r[j] = w3p[j];
        }
        if (tid < 64) {
            for (int j = 0; j < 32; ++j) W2sh[tid * 33 + j] = W2[tid * 32 + j];
        }
        float yv[16];
#pragma unroll
        for (int pp = 0; pp < 16; ++pp) yv[pp] = y[(size_t)(p0 + pp) * ND + tid];
        const float b1r = b1[o];
        const float b2r = b2[tid & 63];
        const float b3r = b3[tid];
#pragma unroll
        for (int pp = 0; pp < 16; ++pp) {
            const float2 hv = ((const float2*)(h + (size_t)(p0 + pp) * NH))[tid];
            ssh[pp * 512 + tid * 2] = hv.x;
            ssh[pp * 512 + tid * 2 + 1] = hv.y;
        }
        __syncthreads();
#pragma unroll
        for (int pp = 0; pp < 16; ++pp) {
            const float4* s4 = (const float4*)&ssh[pp * 512 + seg * 64];
            float p = 0.f;
#pragma unroll
            for (int it = 0; it < 16; ++it) {
                const float4 sv = s4[(it + seg * 2) & 15];  // dynamic LDS idx ok
                const float4 w = w1r[it];                   // static reg idx
                p += w.x * sv.x + w.y * sv.y + w.z * sv.z + w.w * sv.w;
            }
            p += __shfl_xor(p, 1, 64);
            p += __shfl_xor(p, 2, 64);
            p += __shfl_xor(p, 4, 64);
            if (seg == 0) h1sh[pp * 32 + o] = fmaxf(p + b1r, 0.f);
        }
        __syncthreads();
        {
            const int o2 = tid & 63;
#pragma unroll
            for (int it = 0; it < 4; ++it) {
                const int pp = wv * 4 + it;
                float s = b2r;
#pragma unroll
                for (int j = 0; j < 32; ++j) s += W2sh[o2 * 33 + j] * h1sh[pp * 32 + j];
                h2sh[pp * 64 + o2] = fmaxf(s, 0.f);
            }
        }
        __syncthreads();
#pragma unroll
        for (int pp = 0; pp < 16; ++pp) {
            float s = b3r;
            const float4* h24 = (const float4*)&h2sh[pp * 64];
#pragma unroll
            for (int j = 0; j < 16; ++j) {
                const float4 w = w3r[j], hb = h24[j];
                s += w.x * hb.x + w.y * hb.y + w.z * hb.z + w.w * hb.w;
            }
            const float d = yv[pp] - s;
            float sq = d * d;
#pragma unroll
            for (int off = 32; off > 0; off >>= 1) sq += __shfl_xor(sq, off, 64);
            if ((tid & 63) == 0) red[pp * 4 + wv] = sq;
        }
        __syncthreads();
        if (tid < 16) {
            out[OFF_Y + p0 + tid] =
                CY_CONST - 5000.f * (red[tid * 4] + red[tid * 4 + 1] + red[tid * 4 + 2] +
                                     red[tid * 4 + 3]);
        }
    }
}

// ------- big GEMM (32x32x16 MFMA, R6-exact K-loop) -----------------------------
// R13: tn-MAJOR slot order within each XCD. Old tm-major order cycled all 33
// B-panels (6.5MB > 4MB L2) per tm-group -> FETCH_SIZE 215MB (~7x refetch of
// 31.7MB distinct data), and with the syncthreads-drain K-loop every K-step's
// barrier waits on the slowest staging load, putting L2-miss latency straight
// into the critical path. tn-major keeps the XCD's 16 A-panels (3MB) L2-
// resident and streams each B-panel once: predicted FETCH ~90-120MB.
// K-loop stays at R6 local optimum. Failed alternates: LDS-dbuf (R5),
// fixed-B (R7), reg-prefetch (R8), atomic epilogue (R9), 108-VGPR strip (R10),
// 256x256 8-wave counted-vmcnt pipeline (R11: 273us).
__global__ __launch_bounds__(256) void gemm_kernel(const f16* __restrict__ A,
                                                   const f16* __restrict__ Bm,
                                                   const float* __restrict__ biasc,
                                                   const float* __restrict__ sampled_h,
                                                   float* __restrict__ sq_part,
                                                   float* __restrict__ Ps) {
    __shared__ __align__(16) f16 Ash[8 * 128 * 8];
    __shared__ __align__(16) f16 Bsh[8 * 128 * 8];
    const int tid = threadIdx.x;
    const int lane = tid & 63;
    const int wave = tid >> 6;
    const int xcd = blockIdx.x & 7;
    const int slot = blockIdx.x >> 3;  // 0..527
    const int tm = xcd * 16 + (slot & 15);  // R13: tn-major
    const int tn = slot >> 4;               // 0..32
    const int m0 = tm * 128, n0 = tn * 128;
    const int l31 = lane & 31, hk = lane >> 5;

    f32x16 acc[4];
#pragma unroll
    for (int a = 0; a < 4; ++a) acc[a] = (f32x16)0.f;

    for (int kk = 0; kk < RDIM; kk += 64) {
        __syncthreads();
        const size_t abase = (size_t)tm * TILE_ELEMS + (size_t)kk * 128;
        const size_t bbase = (size_t)tn * TILE_ELEMS + (size_t)kk * 128;
#pragma unroll
        for (int inst = 0; inst < 4; ++inst) {
            const int fb = inst * 256 + wave * 64;  // wave-uniform
            const f16* ga = A + abase + (size_t)(fb + lane) * 8;  // contiguous 1KB/inst
            const f16* gb = Bm + bbase + (size_t)(fb + lane) * 8;
            __builtin_amdgcn_global_load_lds(
                (const __attribute__((address_space(1))) void*)ga,
                (__attribute__((address_space(3))) void*)&Ash[fb * 8], 16, 0, 0);
            __builtin_amdgcn_global_load_lds(
                (const __attribute__((address_space(1))) void*)gb,
                (__attribute__((address_space(3))) void*)&Bsh[fb * 8], 16, 0, 0);
        }
        __syncthreads();
#pragma unroll
        for (int kc = 0; kc < 4; ++kc) {
            const int ch = kc * 2 + hk;
            const f16x8 af = *(const f16x8*)&Ash[(ch * 128 + wave * 32 + l31) * 8];
            f16x8 bfr[4];
#pragma unroll
            for (int ni = 0; ni < 4; ++ni)
                bfr[ni] = *(const f16x8*)&Bsh[(ch * 128 + ni * 32 + l31) * 8];
#pragma unroll
            for (int ni = 0; ni < 4; ++ni)
                acc[ni] = __builtin_amdgcn_mfma_f32_32x32x16_f16(af, bfr[ni], acc[ni], 0, 0, 0);
        }
    }

    // epilogue: C layout col=lane&31, row=(reg&3)+8*(reg>>2)+4*(lane>>5)
    if (tn == 32) {  // ---- trans: tanh + column log-softmax over i (c = i*8+j)
        const float bt0 = biasc[4096 + l31];
        const float bt1 = biasc[4096 + 32 + l31];
#pragma unroll
        for (int r = 0; r < 16; ++r) {
            const int mg = m0 + wave * 32 + (r & 3) + 8 * (r >> 2) + 4 * hk;
            if (mg < M_REAL) {
                const float v0 = ftanh(acc[0][r] + bt0);  // c = l31   (i = 0..3)
                const float v1 = ftanh(acc[1][r] + bt1);  // c = 32+l31 (i = 4..7)
                float M = fmaxf(v0, v1);
                M = fmaxf(M, __shfl_xor(M, 8, 64));
                M = fmaxf(M, __shfl_xor(M, 16, 64));
                float s = fexp2((v0 - M) * LOG2E) + fexp2((v1 - M) * LOG2E);
                s += __shfl_xor(s, 8, 64);
                s += __shfl_xor(s, 16, 64);
                const float lse = M + LN2 * flog2(s);
                const int b = mg / 511, t = mg - b * 511;
                const size_t base = (size_t)(b * NT + t + 1) * 64;
                Ps[base + l31] = v0 - lse;
                Ps[base + 32 + l31] = v1 - lse;
            }
        }
    } else {  // ---- sq epilogue: full-width rows per wave -> one slot, shfl only
        const int k0 = n0 >> 9;
        const int slot4 = (n0 >> 7) & 3;
        const float b0 = biasc[n0 + l31];
        const float b1v = biasc[n0 + 32 + l31];
        const float b2v = biasc[n0 + 64 + l31];
        const float b3v = biasc[n0 + 96 + l31];
#pragma unroll
        for (int r = 0; r < 16; ++r) {
            const int mg = m0 + wave * 32 + (r & 3) + 8 * (r >> 2) + 4 * hk;
            if (mg < M_REAL) {
                const int bb = mg / 511;
                const int tt = mg - bb * 511;
                const float* tgt = sampled_h + (size_t)((bb << 9) + tt + 1) * NH;
                const float d0 = tgt[(n0 + l31) & 511] - ftanh(acc[0][r] + b0);
                const float d1 = tgt[(n0 + 32 + l31) & 511] - ftanh(acc[1][r] + b1v);
                const float d2 = tgt[(n0 + 64 + l31) & 511] - ftanh(acc[2][r] + b2v);
                const float d3 = tgt[(n0 + 96 + l31) & 511] - ftanh(acc[3][r] + b3v);
                float rs = d0 * d0 + d1 * d1 + d2 * d2 + d3 * d3;
                rs += __shfl_xor(rs, 1, 64);
                rs += __shfl_xor(rs, 2, 64);
                rs += __shfl_xor(rs, 4, 64);
                rs += __shfl_xor(rs, 8, 64);
                rs += __shfl_xor(rs, 16, 64);
                if (l31 == 0) sq_part[(size_t)(mg * 8 + k0) * 4 + slot4] = rs;
            }
        }
    }
}

// ------ post: finalize_h + s0 + pinit ----
__global__ void post_kernel(const float* __restrict__ sq_part,
                            const float* __restrict__ initials, float* __restrict__ out) {
    const int g = blockIdx.x * 256 + threadIdx.x;  // < 131072
    const int b = g >> 12;
    const int t = (g >> 3) & 511;
    const int k = g & 7;
    float val;
    if (t == 0) {
        val = CH_CONST;
    } else {
        const int m = b * 511 + (t - 1);
        const float4 a = *(const float4*)&sq_part[(size_t)(m * 8 + k) * 4];
        val = CH_CONST - 5000.f * (a.x + a.y + a.z + a.w);
    }
    out[OFF_H + g] = val;
    if (g < 2048) {
        const int sb = g >> 6, c = g & 63;
        out[OFF_S + (size_t)sb * NT * 64 + c] = ((c >> 3) == (c & 7)) ? 1.f : 0.f;
    }
    if (g < 256) {
        float z[8];
#pragma unroll
        for (int j = 0; j < 8; ++j) z[j] = initials[j];
        out[OFF_PI + g] = z[g & 7] - lse8v(z);
    }
}

// ------- forward / backward scans: shfl-only + depth-8 register pipeline -------
__global__ __launch_bounds__(256) void scan_kernel(const float* __restrict__ initials,
                                                   float* __restrict__ out) {
    const float* Ps = out + OFF_S;
    const float* Ph = out + OFF_H;
    const float* Py = out + OFF_Y;
    const int lane = threadIdx.x & 63;
    const int wave = threadIdx.x >> 6;
    const int b = wave * 8 + (lane >> 3);
    const int i = lane & 7;
    const int lbase = lane & ~7;

    if (blockIdx.x == 0) {
        float z0[8];
#pragma unroll
        for (int j = 0; j < 8; ++j) z0[j] = initials[j];
        float* Fw = out + OFF_F;
        float a = (z0[i] - lse8v(z0)) + CH_CONST + Py[b * NT];
        Fw[(size_t)(b * NT) * 8 + i] = a;
        float4 cA[8], cB[8]; float cH[8], cY[8];
        float4 nA[8], nB[8]; float nH[8], nY[8];
#define FLOAD(CC, A_, B_, H_, Y_)                                                  \
        _Pragma("unroll") for (int j = 0; j < 8; ++j) {                            \
            int t = 1 + (CC) * 8 + j;                                              \
            t = t > 511 ? 511 : t;                                                 \
            const size_t p = (size_t)(b * NT + t) * 64 + i * 8;                    \
            A_[j] = *(const float4*)&Ps[p];                                        \
            B_[j] = *(const float4*)&Ps[p + 4];                                    \
            H_[j] = Ph[(size_t)(b * NT + t) * 8 + i];                              \
            Y_[j] = Py[b * NT + t];                                                \
        }
#define FSTEP(CC, A_, B_, H_, Y_)                                                  \
        _Pragma("unroll") for (int j = 0; j < 8; ++j) {                            \
            const int t = 1 + (CC) * 8 + j;                                        \
            if (t < NT) {                                                          \
                float z[8];                                                        \
                z[0] = __shfl(a, lbase + 0, 64) + A_[j].x;                         \
                z[1] = __shfl(a, lbase + 1, 64) + A_[j].y;                         \
                z[2] = __shfl(a, lbase + 2, 64) + A_[j].z;                         \
                z[3] = __shfl(a, lbase + 3, 64) + A_[j].w;                         \
                z[4] = __shfl(a, lbase + 4, 64) + B_[j].x;                         \
                z[5] = __shfl(a, lbase + 5, 64) + B_[j].y;                         \
                z[6] = __shfl(a, lbase + 6, 64) + B_[j].z;                         \
                z[7] = __shfl(a, lbase + 7, 64) + B_[j].w;                         \
                a = (H_[j] + Y_[j]) + lse8v(z);                                    \
                Fw[(size_t)(b * NT + t) * 8 + i] = a;                              \
            }                                                                      \
        }
        FLOAD(0, cA, cB, cH, cY);
        for (int c = 0; c < 64; c += 2) {
            const int c1 = c + 1;
            const int c2 = (c + 2 < 64) ? c + 2 : 63;
            FLOAD(c1, nA, nB, nH, nY);
            FSTEP(c, cA, cB, cH, cY);
            FLOAD(c2, cA, cB, cH, cY);
            FSTEP(c1, nA, nB, nH, nY);
        }
#undef FLOAD
#undef FSTEP
    } else {
        float* Bw = out + OFF_BW;
        float bv = 0.f;
        Bw[(size_t)(b * NT + NT - 1) * 8 + i] = 0.f;
        float cS[8][8], nS[8][8]; float cH[8], cY[8], nH[8], nY[8];
#define BLOAD(CC, S_, H_, Y_)                                                      \
        _Pragma("unroll") for (int j = 0; j < 8; ++j) {                            \
            int t = 510 - ((CC) * 8 + j);                                          \
            t = t < 0 ? 0 : t;                                                     \
            const size_t t1 = (size_t)(b * NT + t + 1);                            \
            _Pragma("unroll") for (int ii = 0; ii < 8; ++ii)                       \
                S_[j][ii] = Ps[t1 * 64 + ii * 8 + i];                              \
            H_[j] = Ph[t1 * 8 + i];                                                \
            Y_[j] = Py[t1];                                                        \
        }
#define BSTEP(CC, S_, H_, Y_)                                                      \
        _Pragma("unroll") for (int j = 0; j < 8; ++j) {                            \
            const int t = 510 - ((CC) * 8 + j);                                    \
            if (t >= 0) {                                                          \
                const float v = H_[j] + Y_[j] + bv;                                \
                float z[8];                                                        \
                _Pragma("unroll") for (int ii = 0; ii < 8; ++ii)                   \
                    z[ii] = __shfl(v, lbase + ii, 64) + S_[j][ii];                 \
                bv = lse8v(z);                                                     \
                Bw[(size_t)(b * NT + t) * 8 + i] = bv;                             \
            }                                                                      \
        }
        BLOAD(0, cS, cH, cY);
        for (int c = 0; c < 64; c += 2) {
            const int c1 = c + 1;
            const int c2 = (c + 2 < 64) ? c + 2 : 63;
            BLOAD(c1, nS, nH, nY);
            BSTEP(c, cS, cH, cY);
            BLOAD(c2, cS, cH, cY);
            BSTEP(c1, nS, nH, nY);
        }
#undef BLOAD
#undef BSTEP
    }
}

// ---------------- fused gamma2 (511 blocks) + gamma1 (64 blocks) ---------------
__global__ void gamma_kernel(float* __restrict__ out) {
    const float* Ps = out + OFF_S;
    const float* Ph = out + OFF_H;
    const float* Py = out + OFF_Y;
    const float* Fw = out + OFF_F;
    const float* Bw = out + OFF_BW;
    if (blockIdx.x < 511) {
        const int gidx = blockIdx.x * 256 + threadIdx.x;  // < 130816 = 32*511*8
        const int pos = gidx >> 3;                        // b*511 + t
        const int i = gidx & 7;
        const int b = pos / 511, t = pos - b * 511;
        const size_t t1 = (size_t)(b * NT + t + 1);
        const float ei = Ph[t1 * 8 + i] + Py[t1] + Bw[t1 * 8 + i];
        const float4 sa = ((const float4*)&Ps[(t1 * 8 + i) * 8])[0];
        const float4 sb = ((const float4*)&Ps[(t1 * 8 + i) * 8])[1];
        const float4 fa = ((const float4*)&Fw[(size_t)(b * NT + t) * 8])[0];
        const float4 fb = ((const float4*)&Fw[(size_t)(b * NT + t) * 8])[1];
        float z[8] = {fa.x + sa.x + ei, fa.y + sa.y + ei, fa.z + sa.z + ei, fa.w + sa.w + ei,
                      fb.x + sb.x + ei, fb.y + sb.y + ei, fb.z + sb.z + ei, fb.w + sb.w + ei};
        float M = fmaxf(fmaxf(fmaxf(z[0], z[1]), fmaxf(z[2], z[3])),
                        fmaxf(fmaxf(z[4], z[5]), fmaxf(z[6], z[7])));
        M = fmaxf(M, __shfl_xor(M, 1, 64));
        M = fmaxf(M, __shfl_xor(M, 2, 64));
        M = fmaxf(M, __shfl_xor(M, 4, 64));
        float s = 0.f;
#pragma unroll
        for (int j = 0; j < 8; ++j) s += fexp2((z[j] - M) * LOG2E);
        s += __shfl_xor(s, 1, 64);
        s += __shfl_xor(s, 2, 64);
        s += __shfl_xor(s, 4, 64);
        const float l = M + LN2 * flog2(s);
        float* G2 = out + OFF_G2;
        float4 o0 = {z[0] - l, z[1] - l, z[2] - l, z[3] - l};
        float4 o1 = {z[4] - l, z[5] - l, z[6] - l, z[7] - l};
        ((float4*)&G2[(size_t)gidx * 8])[0] = o0;
        ((float4*)&G2[(size_t)gidx * 8])[1] = o1;
    } else {
        const int pos = (blockIdx.x - 511) * 256 + threadIdx.x;  // < 16384
        const float4 fa = ((const float4*)&Fw[(size_t)pos * 8])[0];
        const float4 fb = ((const float4*)&Fw[(size_t)pos * 8])[1];
        const float4 ba = ((const float4*)&Bw[(size_t)pos * 8])[0];
        const float4 bb = ((const float4*)&Bw[(size_t)pos * 8])[1];
        float ab[8] = {fa.x + ba.x, fa.y + ba.y, fa.z + ba.z, fa.w + ba.w,
                       fb.x + bb.x, fb.y + bb.y, fb.z + bb.z, fb.w + bb.w};
        const float l = lse8v(ab);
        float* G1 = out + OFF_G1;
        float4 o0 = {ab[0] - l, ab[1] - l, ab[2] - l, ab[3] - l};
        float4 o1 = {ab[4] - l, ab[5] - l, ab[6] - l, ab[7] - l};
        ((float4*)&G1[(size_t)pos * 8])[0] = o0;
        ((float4*)&G1[(size_t)pos * 8])[1] = o1;
    }
}

extern "C" void kernel_launch(void* const* d_in, const int* in_sizes, int n_in, void* d_out,
                              int out_size, void* d_ws, size_t ws_size, hipStream_t stream) {
    const float* x = (const float*)d_in[0];
    const float* y = (const float*)d_in[1];
    const float* h = (const float*)d_in[2];
    const float* initials = (const float*)d_in[3];
    const float* Wih = (const float*)d_in[4];
    const float* Whh = (const float*)d_in[5];
    const float* bih = (const float*)d_in[6];
    const float* bhh = (const float*)d_in[7];
    const float* Wt = (const float*)d_in[8];
    const float* btv = (const float*)d_in[9];
    const float* W1 = (const float*)d_in[10];
    const float* b1 = (const float*)d_in[11];
    const float* W2 = (const float*)d_in[12];
    const float* b2 = (const float*)d_in[13];
    const float* W3 = (const float*)d_in[14];
    const float* b3 = (const float*)d_in[15];
    float* out = (float*)d_out;
    char* ws = (char*)d_ws;
    if (ws_size < (size_t)WS_NEED) return;
    f16* Aws = (f16*)(ws + WS_A);
    f16* Bws = (f16*)(ws + WS_B);
    float* biasc = (float*)(ws + WS_BIAS);
    float* sqp = (float*)(ws + WS_SQ);

    conv_kernel<<<CONV_GRID, 256, 0, stream>>>(x, h, y, Wih, Whh, bih, bhh, Wt, btv, W1, b1,
                                               W2, b2, W3, b3, Aws, Bws, biasc, out);
    gemm_kernel<<<4224, 256, 0, stream>>>(Aws, Bws, biasc, h, sqp, out + OFF_S);
    post_kernel<<<512, 256, 0, stream>>>(sqp, initials, out);
    scan_kernel<<<2, 256, 0, stream>>>(initials, out);
    gamma_kernel<<<575, 256, 0, stream>>>(out);
}

// Round 5
// 388.237 us; speedup vs baseline: 1.1900x; 1.1900x over previous
//
#include <hip/hip_runtime.h>

typedef _Float16 f16;
typedef _Float16 f16x8 __attribute__((ext_vector_type(8)));
typedef float f32x16 __attribute__((ext_vector_type(16)));

#define NB 32
#define NT 512
#define ND 256
#define NH 512
#define M_REAL 16352   // NB*(NT-1)
#define RDIM 768       // ND + NH
#define TILE_ELEMS 98304  // 96 ch * 128 rows * 8 f16 per tile
#define NTN 33            // 32 real n-tiles + 1 trans tile (cols 4096..4223)

// output offsets (floats)
#define OFF_PI 0
#define OFF_S  256
#define OFF_H  1048832
#define OFF_Y  1179904
#define OFF_G1 1196288
#define OFF_G2 1327360
#define OFF_F  2373888
#define OFF_BW 2504960

// ws offsets (bytes)
#define WS_A    0            // f16 tiled [128][96][128][8] = 25165824 B
#define WS_B    25165824     // f16 tiled [33][96][128][8]  = 6488064 B
#define WS_BIAS 31653888     // f32 [4224]
#define WS_SQ   31671296     // f32 [16384][8][4] = 2097152 B
#define WS_M    33768448     // f32 [2][32][16][64] chunk transfer matrices = 524288 B
#define WS_NEED 34292736

#define CH_CONST 1887.3506062251f   // -0.5*512*(log(2pi)+log(1e-4))
#define CY_CONST 943.6753031126f    // -0.5*256*(...)
#define LOG2E 1.4426950408889634f
#define LN2 0.6931471805599453f
#define NEGINF -1e30f

// conv grid layout (R12): 16-row chunks through LDS transpose
#define CA_BLOCKS 1024   // 16384/16 rows of A
#define CB_BLOCKS 264    // 4224/16 rows of B
#define EM_BASE   1288   // CA_BLOCKS + CB_BLOCKS
#define CONV_GRID 2312   // EM_BASE + 16384/16 emission blocks

__device__ __forceinline__ float fexp2(float x) { return __builtin_amdgcn_exp2f(x); }
__device__ __forceinline__ float flog2(float x) { return __builtin_amdgcn_logf(x); }
__device__ __forceinline__ float ftanh(float x) {
    x = fminf(10.f, fmaxf(-10.f, x));
    float t = fexp2(x * 2.885390081777927f);  // 2*log2(e)
    return (t - 1.f) * __builtin_amdgcn_rcpf(t + 1.f);
}
// pairwise-tree max AND sum (R13) — short serial dependency chain.
__device__ __forceinline__ float lse8v(const float* z) {
    float M = fmaxf(fmaxf(fmaxf(z[0], z[1]), fmaxf(z[2], z[3])),
                    fmaxf(fmaxf(z[4], z[5]), fmaxf(z[6], z[7])));
    const float e0 = fexp2((z[0] - M) * LOG2E), e1 = fexp2((z[1] - M) * LOG2E);
    const float e2 = fexp2((z[2] - M) * LOG2E), e3 = fexp2((z[3] - M) * LOG2E);
    const float e4 = fexp2((z[4] - M) * LOG2E), e5 = fexp2((z[5] - M) * LOG2E);
    const float e6 = fexp2((z[6] - M) * LOG2E), e7 = fexp2((z[7] - M) * LOG2E);
    const float s = ((e0 + e1) + (e2 + e3)) + ((e4 + e5) + (e6 + e7));
    return M + LN2 * flog2(s);
}

// -------- conv (A + extended B incl. Wt tile) | emission, one kernel ----------
// tiled index for (row m, col c): (m>>7)*98304 + (c>>3)*1024 + (m&127)*8 + (c&7)
// R12: conv_a/conv_b stage through a padded LDS tile so GLOBAL WRITES are
// m-fastest (256B-contiguous segments). Reads keep coalesced ch-fastest order.
__global__ __launch_bounds__(256) void conv_kernel(
    const float* __restrict__ x, const float* __restrict__ h, const float* __restrict__ y,
    const float* __restrict__ Wih, const float* __restrict__ Whh,
    const float* __restrict__ bih, const float* __restrict__ bhh,
    const float* __restrict__ Wt, const float* __restrict__ btv,
    const float* __restrict__ W1, const float* __restrict__ b1,
    const float* __restrict__ W2, const float* __restrict__ b2,
    const float* __restrict__ W3, const float* __restrict__ b3, f16* __restrict__ A,
    f16* __restrict__ Bm, float* __restrict__ biasc, float* __restrict__ out) {
    __shared__ __align__(16) float smem[11904];  // emission arena / conv transpose buf
    const int tid = threadIdx.x;
    if (blockIdx.x < CA_BLOCKS) {  // -------- conv_a: 16 rows x 96 ch --------
        const int m0 = blockIdx.x * 16;
        f16x8* tb = (f16x8*)smem;  // [16][97] padded
#pragma unroll
        for (int i = 0; i < 6; ++i) {
            const int idx = tid + 256 * i;  // 0..1535
            const int ml = idx / 96;
            const int ch = idx - ml * 96;
            const int m = m0 + ml;
            f16x8 pk = (f16x8)(f16)0.f;
            if (m < M_REAL) {
                const int b = m / 511;
                const int t = m - b * 511;
                const int c0 = ch * 8;
                const float* src = (c0 < ND) ? x + (size_t)(b * NT + t + 1) * ND + c0
                                             : h + (size_t)(b * NT + t) * NH + (c0 - ND);
                const float4 u = ((const float4*)src)[0];
                const float4 v = ((const float4*)src)[1];
                pk[0] = (f16)u.x; pk[1] = (f16)u.y; pk[2] = (f16)u.z; pk[3] = (f16)u.w;
                pk[4] = (f16)v.x; pk[5] = (f16)v.y; pk[6] = (f16)v.z; pk[7] = (f16)v.w;
            }
            tb[ml * 97 + ch] = pk;
        }
        __syncthreads();
        const size_t tbase = (size_t)(m0 >> 7) * TILE_ELEMS + (size_t)(m0 & 127) * 8;
#pragma unroll
        for (int i = 0; i < 6; ++i) {
            const int idx = tid + 256 * i;
            const int ch2 = idx >> 4;
            const int m2 = idx & 15;
            *(f16x8*)(A + tbase + (size_t)ch2 * 1024 + (size_t)m2 * 8) = tb[m2 * 97 + ch2];
        }
    } else if (blockIdx.x < EM_BASE) {  // -------- conv_b: 16 rows x 96 ch ------
        const int n0 = (blockIdx.x - CA_BLOCKS) * 16;
        f16x8* tb = (f16x8*)smem;  // [16][97]
#pragma unroll
        for (int i = 0; i < 6; ++i) {
            const int idx = tid + 256 * i;
            const int nl = idx / 96;
            const int ch = idx - nl * 96;
            const int n = n0 + nl;
            const int c0 = ch * 8;
            f16x8 pk = (f16x8)(f16)0.f;
            const float* src = nullptr;
            if (n < 4096) {
                src = (c0 < ND) ? Wih + (size_t)n * ND + c0 : Whh + (size_t)n * NH + (c0 - ND);
            } else {
                const int c = n - 4096;
                if (c < 64 && c0 >= ND) src = Wt + (size_t)c * NH + (c0 - ND);
            }
            if (src) {
                const float4 u = ((const float4*)src)[0];
                const float4 v = ((const float4*)src)[1];
                pk[0] = (f16)u.x; pk[1] = (f16)u.y; pk[2] = (f16)u.z; pk[3] = (f16)u.w;
                pk[4] = (f16)v.x; pk[5] = (f16)v.y; pk[6] = (f16)v.z; pk[7] = (f16)v.w;
            }
            tb[nl * 97 + ch] = pk;
        }
        if (tid < 16) {
            const int n = n0 + tid;
            biasc[n] = (n < 4096) ? bih[n] + bhh[n] : ((n - 4096) < 64 ? btv[n - 4096] : 0.f);
        }
        __syncthreads();
        const size_t tbase = (size_t)(n0 >> 7) * TILE_ELEMS + (size_t)(n0 & 127) * 8;
#pragma unroll
        for (int i = 0; i < 6; ++i) {
            const int idx = tid + 256 * i;
            const int ch2 = idx >> 4;
            const int m2 = idx & 15;
            *(f16x8*)(Bm + tbase + (size_t)ch2 * 1024 + (size_t)m2 * 8) = tb[m2 * 97 + ch2];
        }
    } else {  // -------- emission MLP + gaussian lp --------
        float* ssh = smem;           // 16*512
        float* W2sh = smem + 8192;   // 64*33
        float* h1sh = smem + 10304;  // 16*32
        float* h2sh = smem + 10816;  // 16*64
        float* red = smem + 11840;   // 16*4
        const int wv = tid >> 6;
        const int o = tid >> 3, seg = tid & 7;
        const int p0 = (blockIdx.x - EM_BASE) * 16;
        float4 w1r[16], w3r[16];
        {
            const float4* w1p = (const float4*)(W1 + (size_t)o * NH + seg * 64);
#pragma unroll
            for (int j = 0; j < 16; ++j) w1r[j] = w1p[(j + seg * 2) & 15];  // staggered
            const float4* w3p = (const float4*)(W3 + (size_t)tid * 64);
#pragma unroll
            for (int j = 0; j < 16; ++j) w3r[j] = w3p[j];
        }
        if (tid < 64) {
            for (int j = 0; j < 32; ++j) W2sh[tid * 33 + j] = W2[tid * 32 + j];
        }
        float yv[16];
#pragma unroll
        for (int pp = 0; pp < 16; ++pp) yv[pp] = y[(size_t)(p0 + pp) * ND + tid];
        const float b1r = b1[o];
        const float b2r = b2[tid & 63];
        const float b3r = b3[tid];
#pragma unroll
        for (int pp = 0; pp < 16; ++pp) {
            const float2 hv = ((const float2*)(h + (size_t)(p0 + pp) * NH))[tid];
            ssh[pp * 512 + tid * 2] = hv.x;
            ssh[pp * 512 + tid * 2 + 1] = hv.y;
        }
        __syncthreads();
#pragma unroll
        for (int pp = 0; pp < 16; ++pp) {
            const float4* s4 = (const float4*)&ssh[pp * 512 + seg * 64];
            float p = 0.f;
#pragma unroll
            for (int it = 0; it < 16; ++it) {
                const float4 sv = s4[(it + seg * 2) & 15];  // dynamic LDS idx ok
                const float4 w = w1r[it];                   // static reg idx
                p += w.x * sv.x + w.y * sv.y + w.z * sv.z + w.w * sv.w;
            }
            p += __shfl_xor(p, 1, 64);
            p += __shfl_xor(p, 2, 64);
            p += __shfl_xor(p, 4, 64);
            if (seg == 0) h1sh[pp * 32 + o] = fmaxf(p + b1r, 0.f);
        }
        __syncthreads();
        {
            const int o2 = tid & 63;
#pragma unroll
            for (int it = 0; it < 4; ++it) {
                const int pp = wv * 4 + it;
                float s = b2r;
#pragma unroll
                for (int j = 0; j < 32; ++j) s += W2sh[o2 * 33 + j] * h1sh[pp * 32 + j];
                h2sh[pp * 64 + o2] = fmaxf(s, 0.f);
            }
        }
        __syncthreads();
#pragma unroll
        for (int pp = 0; pp < 16; ++pp) {
            float s = b3r;
            const float4* h24 = (const float4*)&h2sh[pp * 64];
#pragma unroll
            for (int j = 0; j < 16; ++j) {
                const float4 w = w3r[j], hb = h24[j];
                s += w.x * hb.x + w.y * hb.y + w.z * hb.z + w.w * hb.w;
            }
            const float d = yv[pp] - s;
            float sq = d * d;
#pragma unroll
            for (int off = 32; off > 0; off >>= 1) sq += __shfl_xor(sq, off, 64);
            if ((tid & 63) == 0) red[pp * 4 + wv] = sq;
        }
        __syncthreads();
        if (tid < 16) {
            out[OFF_Y + p0 + tid] =
                CY_CONST - 5000.f * (red[tid * 4] + red[tid * 4 + 1] + red[tid * 4 + 2] +
                                     red[tid * 4 + 3]);
        }
    }
}

// ------- big GEMM (32x32x16 MFMA, R6-exact K-loop, R12 tm-major order) ---------
// FROZEN at the measured-best config (158.8us). Failed alternates: LDS-dbuf
// (R5), fixed-B (R7), reg-prefetch (R8), atomic epilogue (R9), 108-VGPR strip
// (R10), 256x256 counted-vmcnt pipeline (R11: 273us), tn-major remap (R13:
// FETCH -11% but WRITE +40% from lost sq_part write-combining; dur +2.6us —
// kernel is structure-bound at the m97 barrier-drain ceiling, not fetch-bound).
__global__ __launch_bounds__(256) void gemm_kernel(const f16* __restrict__ A,
                                                   const f16* __restrict__ Bm,
                                                   const float* __restrict__ biasc,
                                                   const float* __restrict__ sampled_h,
                                                   float* __restrict__ sq_part,
                                                   float* __restrict__ Ps) {
    __shared__ __align__(16) f16 Ash[8 * 128 * 8];
    __shared__ __align__(16) f16 Bsh[8 * 128 * 8];
    const int tid = threadIdx.x;
    const int lane = tid & 63;
    const int wave = tid >> 6;
    const int xcd = blockIdx.x & 7;
    const int slot = blockIdx.x >> 3;  // 0..527
    const int tm = xcd * 16 + slot / NTN;
    const int tn = slot % NTN;
    const int m0 = tm * 128, n0 = tn * 128;
    const int l31 = lane & 31, hk = lane >> 5;

    f32x16 acc[4];
#pragma unroll
    for (int a = 0; a < 4; ++a) acc[a] = (f32x16)0.f;

    for (int kk = 0; kk < RDIM; kk += 64) {
        __syncthreads();
        const size_t abase = (size_t)tm * TILE_ELEMS + (size_t)kk * 128;
        const size_t bbase = (size_t)tn * TILE_ELEMS + (size_t)kk * 128;
#pragma unroll
        for (int inst = 0; inst < 4; ++inst) {
            const int fb = inst * 256 + wave * 64;  // wave-uniform
            const f16* ga = A + abase + (size_t)(fb + lane) * 8;  // contiguous 1KB/inst
            const f16* gb = Bm + bbase + (size_t)(fb + lane) * 8;
            __builtin_amdgcn_global_load_lds(
                (const __attribute__((address_space(1))) void*)ga,
                (__attribute__((address_space(3))) void*)&Ash[fb * 8], 16, 0, 0);
            __builtin_amdgcn_global_load_lds(
                (const __attribute__((address_space(1))) void*)gb,
                (__attribute__((address_space(3))) void*)&Bsh[fb * 8], 16, 0, 0);
        }
        __syncthreads();
#pragma unroll
        for (int kc = 0; kc < 4; ++kc) {
            const int ch = kc * 2 + hk;
            const f16x8 af = *(const f16x8*)&Ash[(ch * 128 + wave * 32 + l31) * 8];
            f16x8 bfr[4];
#pragma unroll
            for (int ni = 0; ni < 4; ++ni)
                bfr[ni] = *(const f16x8*)&Bsh[(ch * 128 + ni * 32 + l31) * 8];
#pragma unroll
            for (int ni = 0; ni < 4; ++ni)
                acc[ni] = __builtin_amdgcn_mfma_f32_32x32x16_f16(af, bfr[ni], acc[ni], 0, 0, 0);
        }
    }

    // epilogue: C layout col=lane&31, row=(reg&3)+8*(reg>>2)+4*(lane>>5)
    if (tn == 32) {  // ---- trans: tanh + column log-softmax over i (c = i*8+j)
        const float bt0 = biasc[4096 + l31];
        const float bt1 = biasc[4096 + 32 + l31];
#pragma unroll
        for (int r = 0; r < 16; ++r) {
            const int mg = m0 + wave * 32 + (r & 3) + 8 * (r >> 2) + 4 * hk;
            if (mg < M_REAL) {
                const float v0 = ftanh(acc[0][r] + bt0);  // c = l31   (i = 0..3)
                const float v1 = ftanh(acc[1][r] + bt1);  // c = 32+l31 (i = 4..7)
                float M = fmaxf(v0, v1);
                M = fmaxf(M, __shfl_xor(M, 8, 64));
                M = fmaxf(M, __shfl_xor(M, 16, 64));
                float s = fexp2((v0 - M) * LOG2E) + fexp2((v1 - M) * LOG2E);
                s += __shfl_xor(s, 8, 64);
                s += __shfl_xor(s, 16, 64);
                const float lse = M + LN2 * flog2(s);
                const int b = mg / 511, t = mg - b * 511;
                const size_t base = (size_t)(b * NT + t + 1) * 64;
                Ps[base + l31] = v0 - lse;
                Ps[base + 32 + l31] = v1 - lse;
            }
        }
    } else {  // ---- sq epilogue: full-width rows per wave -> one slot, shfl only
        const int k0 = n0 >> 9;
        const int slot4 = (n0 >> 7) & 3;
        const float b0 = biasc[n0 + l31];
        const float b1v = biasc[n0 + 32 + l31];
        const float b2v = biasc[n0 + 64 + l31];
        const float b3v = biasc[n0 + 96 + l31];
#pragma unroll
        for (int r = 0; r < 16; ++r) {
            const int mg = m0 + wave * 32 + (r & 3) + 8 * (r >> 2) + 4 * hk;
            if (mg < M_REAL) {
                const int bb = mg / 511;
                const int tt = mg - bb * 511;
                const float* tgt = sampled_h + (size_t)((bb << 9) + tt + 1) * NH;
                const float d0 = tgt[(n0 + l31) & 511] - ftanh(acc[0][r] + b0);
                const float d1 = tgt[(n0 + 32 + l31) & 511] - ftanh(acc[1][r] + b1v);
                const float d2 = tgt[(n0 + 64 + l31) & 511] - ftanh(acc[2][r] + b2v);
                const float d3 = tgt[(n0 + 96 + l31) & 511] - ftanh(acc[3][r] + b3v);
                float rs = d0 * d0 + d1 * d1 + d2 * d2 + d3 * d3;
                rs += __shfl_xor(rs, 1, 64);
                rs += __shfl_xor(rs, 2, 64);
                rs += __shfl_xor(rs, 4, 64);
                rs += __shfl_xor(rs, 8, 64);
                rs += __shfl_xor(rs, 16, 64);
                if (l31 == 0) sq_part[(size_t)(mg * 8 + k0) * 4 + slot4] = rs;
            }
        }
    }
}

// ------ post: finalize_h + s0 + pinit ----
__global__ void post_kernel(const float* __restrict__ sq_part,
                            const float* __restrict__ initials, float* __restrict__ out) {
    const int g = blockIdx.x * 256 + threadIdx.x;  // < 131072
    const int b = g >> 12;
    const int t = (g >> 3) & 511;
    const int k = g & 7;
    float val;
    if (t == 0) {
        val = CH_CONST;
    } else {
        const int m = b * 511 + (t - 1);
        const float4 a = *(const float4*)&sq_part[(size_t)(m * 8 + k) * 4];
        val = CH_CONST - 5000.f * (a.x + a.y + a.z + a.w);
    }
    out[OFF_H + g] = val;
    if (g < 2048) {
        const int sb = g >> 6, c = g & 63;
        out[OFF_S + (size_t)sb * NT * 64 + c] = ((c >> 3) == (c & 7)) ? 1.f : 0.f;
    }
    if (g < 256) {
        float z[8];
#pragma unroll
        for (int j = 0; j < 8; ++j) z[j] = initials[j];
        out[OFF_PI + g] = z[g & 7] - lse8v(z);
    }
}

// ================= R14: chunked parallel scans ================================
// The step a'[i] = E_t[i] + lse_j(a[j] + T_t[i][j]) is an associative affine-
// lse map. 511 steps -> 16 chunks of 32. Phase 1 (scan_mat): each chunk run
// from the 8 basis vectors (lane=(j,i), 64 lanes, same per-step latency as the
// old serial scan but 8 recurrences at once) -> 8x8 transfer matrix in ws.
// Phase 2 (scan_fin): wave for chunk c composes its prefix state (<=15
// pipelined 8x8 lse-applies) then re-runs its 32 steps writing Fw/Bw.
// Serial depth 511 -> ~32 + ~47; parallelism 8 waves -> 1024 waves.

template <bool WRITE>
__device__ __forceinline__ float fwd_run(const float* __restrict__ Ps,
                                         const float* __restrict__ Ph,
                                         const float* __restrict__ Py,
                                         float* __restrict__ Fw, int b, int t0,
                                         int t1, float a, int lane) {
    const int i = lane & 7;
    const int base = lane & ~7;
    float4 cA[8], cB[8], nA[8], nB[8];
    float cH[8], cY[8], nH[8], nY[8];
#define FLOADR(G, A_, B_, H_, Y_)                                              \
    _Pragma("unroll") for (int jj = 0; jj < 8; ++jj) {                         \
        int t = t0 + (G) * 8 + jj;                                             \
        t = t > t1 ? t1 : t;                                                   \
        const size_t p = (size_t)(b * NT + t) * 64 + i * 8;                    \
        A_[jj] = *(const float4*)&Ps[p];                                       \
        B_[jj] = *(const float4*)&Ps[p + 4];                                   \
        H_[jj] = Ph[(size_t)(b * NT + t) * 8 + i];                             \
        Y_[jj] = Py[b * NT + t];                                               \
    }
#define FSTEPR(G, A_, B_, H_, Y_)                                              \
    _Pragma("unroll") for (int jj = 0; jj < 8; ++jj) {                         \
        const int t = t0 + (G) * 8 + jj;                                       \
        if (t <= t1) {                                                         \
            float z[8];                                                        \
            z[0] = __shfl(a, base + 0, 64) + A_[jj].x;                         \
            z[1] = __shfl(a, base + 1, 64) + A_[jj].y;                         \
            z[2] = __shfl(a, base + 2, 64) + A_[jj].z;                         \
            z[3] = __shfl(a, base + 3, 64) + A_[jj].w;                         \
            z[4] = __shfl(a, base + 4, 64) + B_[jj].x;                         \
            z[5] = __shfl(a, base + 5, 64) + B_[jj].y;                         \
            z[6] = __shfl(a, base + 6, 64) + B_[jj].z;                         \
            z[7] = __shfl(a, base + 7, 64) + B_[jj].w;                         \
            a = (H_[jj] + Y_[jj]) + lse8v(z);                                  \
            if (WRITE && lane < 8) Fw[(size_t)(b * NT + t) * 8 + i] = a;       \
        }                                                                      \
    }
    FLOADR(0, cA, cB, cH, cY);
    FLOADR(1, nA, nB, nH, nY);
    FSTEPR(0, cA, cB, cH, cY);
    FLOADR(2, cA, cB, cH, cY);
    FSTEPR(1, nA, nB, nH, nY);
    FLOADR(3, nA, nB, nH, nY);
    FSTEPR(2, cA, cB, cH, cY);
    FSTEPR(3, nA, nB, nH, nY);
#undef FLOADR
#undef FSTEPR
    return a;
}

template <bool WRITE>
__device__ __forceinline__ float bwd_run(const float* __restrict__ Ps,
                                         const float* __restrict__ Ph,
                                         const float* __restrict__ Py,
                                         float* __restrict__ Bw, int b, int tt0,
                                         int tt1, float a, int lane) {
    const int i = lane & 7;
    const int base = lane & ~7;
    float cS[8][8], nS[8][8], cH[8], cY[8], nH[8], nY[8];
#define BLOADR(G, S_, H_, Y_)                                                  \
    _Pragma("unroll") for (int jj = 0; jj < 8; ++jj) {                         \
        int t = tt0 - (G) * 8 - jj;                                            \
        t = t < tt1 ? tt1 : t;                                                 \
        const size_t q = (size_t)(b * NT + t + 1);                             \
        _Pragma("unroll") for (int ii = 0; ii < 8; ++ii)                       \
            S_[jj][ii] = Ps[q * 64 + ii * 8 + i];                              \
        H_[jj] = Ph[q * 8 + i];                                                \
        Y_[jj] = Py[q];                                                       \
    }
#define BSTEPR(G, S_, H_, Y_)                                                  \
    _Pragma("unroll") for (int jj = 0; jj < 8; ++jj) {                         \
        const int t = tt0 - (G) * 8 - jj;                                      \
        if (t >= tt1) {                                                        \
            const float v = H_[jj] + Y_[jj] + a;                               \
            float z[8];                                                        \
            _Pragma("unroll") for (int ii = 0; ii < 8; ++ii)                   \
                z[ii] = __shfl(v, base + ii, 64) + S_[jj][ii];                 \
            a = lse8v(z);                                                      \
            if (WRITE && lane < 8) Bw[(size_t)(b * NT + t) * 8 + i] = a;       \
        }                                                                      \
    }
    BLOADR(0, cS, cH, cY);
    BLOADR(1, nS, nH, nY);
    BSTEPR(0, cS, cH, cY);
    BLOADR(2, cS, cH, cY);
    BSTEPR(1, nS, nH, nY);
    BLOADR(3, nS, nH, nY);
    BSTEPR(2, cS, cH, cY);
    BSTEPR(3, nS, nH, nY);
#undef BLOADR
#undef BSTEPR
    return a;
}

// phase 1: basis runs -> chunk transfer matrices.
// blocks 0..127 fwd (b = blk>>2, c = (blk&3)*4+wave); 128..255 bwd.
__global__ __launch_bounds__(256) void scan_mat_kernel(const float* __restrict__ out,
                                                       float* __restrict__ Mws) {
    const float* Ps = out + OFF_S;
    const float* Ph = out + OFF_H;
    const float* Py = out + OFF_Y;
    const int lane = threadIdx.x & 63;
    const int wave = threadIdx.x >> 6;
    const int i = lane & 7, j = lane >> 3;
    float a = (i == j) ? 0.f : NEGINF;
    if (blockIdx.x < 128) {
        const int b = blockIdx.x >> 2;
        const int c = (blockIdx.x & 3) * 4 + wave;
        const int t0 = 1 + 32 * c;
        const int t1 = (32 * (c + 1) < 511) ? 32 * (c + 1) : 511;
        a = fwd_run<false>(Ps, Ph, Py, nullptr, b, t0, t1, a, lane);
        Mws[(size_t)(b * 16 + c) * 64 + lane] = a;
    } else {
        const int b = (blockIdx.x - 128) >> 2;
        const int c = ((blockIdx.x - 128) & 3) * 4 + wave;
        const int tt0 = 510 - 32 * c;
        const int tt1 = (479 - 32 * c > 0) ? 479 - 32 * c : 0;
        a = bwd_run<false>(Ps, Ph, Py, nullptr, b, tt0, tt1, a, lane);
        Mws[32768 + (size_t)(b * 16 + c) * 64 + lane] = a;
    }
}

// phase 2: prefix-compose (pipelined row loads) then re-run chunk writing out.
__global__ __launch_bounds__(256) void scan_fin_kernel(const float* __restrict__ initials,
                                                       float* __restrict__ out,
                                                       const float* __restrict__ Mws) {
    const float* Ps = out + OFF_S;
    const float* Ph = out + OFF_H;
    const float* Py = out + OFF_Y;
    const int lane = threadIdx.x & 63;
    const int wave = threadIdx.x >> 6;
    const int i = lane & 7;
    const int base = lane & ~7;
    const bool fwd = blockIdx.x < 128;
    const int blk = fwd ? blockIdx.x : blockIdx.x - 128;
    const int b = blk >> 2;
    const int c = (blk & 3) * 4 + wave;
    const float* Mbase = Mws + (fwd ? 0 : 32768) + (size_t)(b * 16) * 64;

    float a;
    if (fwd) {
        float z0[8];
#pragma unroll
        for (int jj = 0; jj < 8; ++jj) z0[jj] = initials[jj];
        a = (z0[i] - lse8v(z0)) + CH_CONST + Py[b * NT];
        if (c == 0 && lane < 8) (out + OFF_F)[(size_t)(b * NT) * 8 + i] = a;
    } else {
        a = 0.f;
        if (c == 0 && lane < 8) (out + OFF_BW)[(size_t)(b * NT + NT - 1) * 8 + i] = 0.f;
    }
    // prefix: apply chunks 0..c-1 (software-pipelined row loads)
    if (c > 0) {
        float4 r0 = *(const float4*)&Mbase[0 * 64 + i * 8];
        float4 r1 = *(const float4*)&Mbase[0 * 64 + i * 8 + 4];
        for (int cc = 0; cc < c; ++cc) {
            float4 s0, s1;
            if (cc + 1 < c) {
                s0 = *(const float4*)&Mbase[(size_t)(cc + 1) * 64 + i * 8];
                s1 = *(const float4*)&Mbase[(size_t)(cc + 1) * 64 + i * 8 + 4];
            }
            float z[8];
            z[0] = __shfl(a, base + 0, 64) + r0.x;
            z[1] = __shfl(a, base + 1, 64) + r0.y;
            z[2] = __shfl(a, base + 2, 64) + r0.z;
            z[3] = __shfl(a, base + 3, 64) + r0.w;
            z[4] = __shfl(a, base + 4, 64) + r1.x;
            z[5] = __shfl(a, base + 5, 64) + r1.y;
            z[6] = __shfl(a, base + 6, 64) + r1.z;
            z[7] = __shfl(a, base + 7, 64) + r1.w;
            a = lse8v(z);
            r0 = s0;
            r1 = s1;
        }
    }
    if (fwd) {
        const int t0 = 1 + 32 * c;
        const int t1 = (32 * (c + 1) < 511) ? 32 * (c + 1) : 511;
        fwd_run<true>(Ps, Ph, Py, out + OFF_F, b, t0, t1, a, lane);
    } else {
        const int tt0 = 510 - 32 * c;
        const int tt1 = (479 - 32 * c > 0) ? 479 - 32 * c : 0;
        bwd_run<true>(Ps, Ph, Py, out + OFF_BW, b, tt0, tt1, a, lane);
    }
}

// ---------------- fused gamma2 (511 blocks) + gamma1 (64 blocks) ---------------
__global__ void gamma_kernel(float* __restrict__ out) {
    const float* Ps = out + OFF_S;
    const float* Ph = out + OFF_H;
    const float* Py = out + OFF_Y;
    const float* Fw = out + OFF_F;
    const float* Bw = out + OFF_BW;
    if (blockIdx.x < 511) {
        const int gidx = blockIdx.x * 256 + threadIdx.x;  // < 130816 = 32*511*8
        const int pos = gidx >> 3;                        // b*511 + t
        const int i = gidx & 7;
        const int b = pos / 511, t = pos - b * 511;
        const size_t t1 = (size_t)(b * NT + t + 1);
        const float ei = Ph[t1 * 8 + i] + Py[t1] + Bw[t1 * 8 + i];
        const float4 sa = ((const float4*)&Ps[(t1 * 8 + i) * 8])[0];
        const float4 sb = ((const float4*)&Ps[(t1 * 8 + i) * 8])[1];
        const float4 fa = ((const float4*)&Fw[(size_t)(b * NT + t) * 8])[0];
        const float4 fb = ((const float4*)&Fw[(size_t)(b * NT + t) * 8])[1];
        float z[8] = {fa.x + sa.x + ei, fa.y + sa.y + ei, fa.z + sa.z + ei, fa.w + sa.w + ei,
                      fb.x + sb.x + ei, fb.y + sb.y + ei, fb.z + sb.z + ei, fb.w + sb.w + ei};
        float M = fmaxf(fmaxf(fmaxf(z[0], z[1]), fmaxf(z[2], z[3])),
                        fmaxf(fmaxf(z[4], z[5]), fmaxf(z[6], z[7])));
        M = fmaxf(M, __shfl_xor(M, 1, 64));
        M = fmaxf(M, __shfl_xor(M, 2, 64));
        M = fmaxf(M, __shfl_xor(M, 4, 64));
        float s = 0.f;
#pragma unroll
        for (int j = 0; j < 8; ++j) s += fexp2((z[j] - M) * LOG2E);
        s += __shfl_xor(s, 1, 64);
        s += __shfl_xor(s, 2, 64);
        s += __shfl_xor(s, 4, 64);
        const float l = M + LN2 * flog2(s);
        float* G2 = out + OFF_G2;
        float4 o0 = {z[0] - l, z[1] - l, z[2] - l, z[3] - l};
        float4 o1 = {z[4] - l, z[5] - l, z[6] - l, z[7] - l};
        ((float4*)&G2[(size_t)gidx * 8])[0] = o0;
        ((float4*)&G2[(size_t)gidx * 8])[1] = o1;
    } else {
        const int pos = (blockIdx.x - 511) * 256 + threadIdx.x;  // < 16384
        const float4 fa = ((const float4*)&Fw[(size_t)pos * 8])[0];
        const float4 fb = ((const float4*)&Fw[(size_t)pos * 8])[1];
        const float4 ba = ((const float4*)&Bw[(size_t)pos * 8])[0];
        const float4 bb = ((const float4*)&Bw[(size_t)pos * 8])[1];
        float ab[8] = {fa.x + ba.x, fa.y + ba.y, fa.z + ba.z, fa.w + ba.w,
                       fb.x + bb.x, fb.y + bb.y, fb.z + bb.z, fb.w + bb.w};
        const float l = lse8v(ab);
        float* G1 = out + OFF_G1;
        float4 o0 = {ab[0] - l, ab[1] - l, ab[2] - l, ab[3] - l};
        float4 o1 = {ab[4] - l, ab[5] - l, ab[6] - l, ab[7] - l};
        ((float4*)&G1[(size_t)pos * 8])[0] = o0;
        ((float4*)&G1[(size_t)pos * 8])[1] = o1;
    }
}

extern "C" void kernel_launch(void* const* d_in, const int* in_sizes, int n_in, void* d_out,
                              int out_size, void* d_ws, size_t ws_size, hipStream_t stream) {
    const float* x = (const float*)d_in[0];
    const float* y = (const float*)d_in[1];
    const float* h = (const float*)d_in[2];
    const float* initials = (const float*)d_in[3];
    const float* Wih = (const float*)d_in[4];
    const float* Whh = (const float*)d_in[5];
    const float* bih = (const float*)d_in[6];
    const float* bhh = (const float*)d_in[7];
    const float* Wt = (const float*)d_in[8];
    const float* btv = (const float*)d_in[9];
    const float* W1 = (const float*)d_in[10];
    const float* b1 = (const float*)d_in[11];
    const float* W2 = (const float*)d_in[12];
    const float* b2 = (const float*)d_in[13];
    const float* W3 = (const float*)d_in[14];
    const float* b3 = (const float*)d_in[15];
    float* out = (float*)d_out;
    char* ws = (char*)d_ws;
    if (ws_size < (size_t)WS_NEED) return;
    f16* Aws = (f16*)(ws + WS_A);
    f16* Bws = (f16*)(ws + WS_B);
    float* biasc = (float*)(ws + WS_BIAS);
    float* sqp = (float*)(ws + WS_SQ);
    float* Mws = (float*)(ws + WS_M);

    conv_kernel<<<CONV_GRID, 256, 0, stream>>>(x, h, y, Wih, Whh, bih, bhh, Wt, btv, W1, b1,
                                               W2, b2, W3, b3, Aws, Bws, biasc, out);
    gemm_kernel<<<4224, 256, 0, stream>>>(Aws, Bws, biasc, h, sqp, out + OFF_S);
    post_kernel<<<512, 256, 0, stream>>>(sqp, initials, out);
    scan_mat_kernel<<<256, 256, 0, stream>>>(out, Mws);
    scan_fin_kernel<<<256, 256, 0, stream>>>(initials, out, Mws);
    gamma_kernel<<<575, 256, 0, stream>>>(out);
}

// Round 7
// 371.646 us; speedup vs baseline: 1.2431x; 1.0446x over previous
//
#include <hip/hip_runtime.h>

typedef _Float16 f16;
typedef _Float16 f16x8 __attribute__((ext_vector_type(8)));
typedef float f32x16 __attribute__((ext_vector_type(16)));

#define NB 32
#define NT 512
#define ND 256
#define NH 512
#define M_REAL 16352   // NB*(NT-1)
#define RDIM 768       // ND + NH
#define TILE_ELEMS 98304  // 96 ch * 128 rows * 8 f16 per tile
#define NTN 33            // 32 real n-tiles + 1 trans tile (cols 4096..4223)

// output offsets (floats)
#define OFF_PI 0
#define OFF_S  256
#define OFF_H  1048832
#define OFF_Y  1179904
#define OFF_G1 1196288
#define OFF_G2 1327360
#define OFF_F  2373888
#define OFF_BW 2504960

// ws offsets (bytes)
#define WS_A    0            // f16 tiled [128][96][128][8] = 25165824 B
#define WS_B    25165824     // f16 tiled [33][96][128][8]  = 6488064 B
#define WS_BIAS 31653888     // f32 [4224]
#define WS_SQ   31671296     // f32 [16384][8][4] = 2097152 B
#define WS_M    33768448     // f32 [2][32][16][64] chunk transfer matrices = 524288 B
#define WS_NEED 34292736

#define CH_CONST 1887.3506062251f   // -0.5*512*(log(2pi)+log(1e-4))
#define CY_CONST 943.6753031126f    // -0.5*256*(...)
#define LOG2E 1.4426950408889634f
#define LN2 0.6931471805599453f
#define NEGINF -1e30f

// conv grid layout (R15): transpose-only kernel; emission split out so the
// register allocator doesn't size the memory-bound transpose blocks for the
// emission branch's ~200 VGPR (w1r+w3r+yv). Lean kernel -> high occupancy.
#define CA_BLOCKS 1024   // 16384/16 rows of A
#define CB_BLOCKS 264    // 4224/16 rows of B
#define CONV_GRID 1288   // CA_BLOCKS + CB_BLOCKS

__device__ __forceinline__ float fexp2(float x) { return __builtin_amdgcn_exp2f(x); }
__device__ __forceinline__ float flog2(float x) { return __builtin_amdgcn_logf(x); }
__device__ __forceinline__ float ftanh(float x) {
    x = fminf(10.f, fmaxf(-10.f, x));
    float t = fexp2(x * 2.885390081777927f);  // 2*log2(e)
    return (t - 1.f) * __builtin_amdgcn_rcpf(t + 1.f);
}
// pairwise-tree max AND sum (R13) — short serial dependency chain.
__device__ __forceinline__ float lse8v(const float* z) {
    float M = fmaxf(fmaxf(fmaxf(z[0], z[1]), fmaxf(z[2], z[3])),
                    fmaxf(fmaxf(z[4], z[5]), fmaxf(z[6], z[7])));
    const float e0 = fexp2((z[0] - M) * LOG2E), e1 = fexp2((z[1] - M) * LOG2E);
    const float e2 = fexp2((z[2] - M) * LOG2E), e3 = fexp2((z[3] - M) * LOG2E);
    const float e4 = fexp2((z[4] - M) * LOG2E), e5 = fexp2((z[5] - M) * LOG2E);
    const float e6 = fexp2((z[6] - M) * LOG2E), e7 = fexp2((z[7] - M) * LOG2E);
    const float s = ((e0 + e1) + (e2 + e3)) + ((e4 + e5) + (e6 + e7));
    return M + LN2 * flog2(s);
}

// -------- conv_ab: A + extended B (incl. Wt tile) tiling, LEAN kernel ---------
// tiled index for (row m, col c): (m>>7)*98304 + (c>>3)*1024 + (m&127)*8 + (c&7)
// R12: stage through a padded LDS tile so GLOBAL WRITES are m-fastest
// (256B-contiguous segments). Reads keep coalesced ch-fastest order.
__global__ __launch_bounds__(256) void conv_ab_kernel(
    const float* __restrict__ x, const float* __restrict__ h,
    const float* __restrict__ Wih, const float* __restrict__ Whh,
    const float* __restrict__ bih, const float* __restrict__ bhh,
    const float* __restrict__ Wt, const float* __restrict__ btv,
    f16* __restrict__ A, f16* __restrict__ Bm, float* __restrict__ biasc) {
    __shared__ __align__(16) f16x8 tb[16 * 97];  // [16][97] padded
    const int tid = threadIdx.x;
    if (blockIdx.x < CA_BLOCKS) {  // -------- conv_a: 16 rows x 96 ch --------
        const int m0 = blockIdx.x * 16;
#pragma unroll
        for (int i = 0; i < 6; ++i) {
            const int idx = tid + 256 * i;  // 0..1535
            const int ml = idx / 96;
            const int ch = idx - ml * 96;
            const int m = m0 + ml;
            f16x8 pk = (f16x8)(f16)0.f;
            if (m < M_REAL) {
                const int b = m / 511;
                const int t = m - b * 511;
                const int c0 = ch * 8;
                const float* src = (c0 < ND) ? x + (size_t)(b * NT + t + 1) * ND + c0
                                             : h + (size_t)(b * NT + t) * NH + (c0 - ND);
                const float4 u = ((const float4*)src)[0];
                const float4 v = ((const float4*)src)[1];
                pk[0] = (f16)u.x; pk[1] = (f16)u.y; pk[2] = (f16)u.z; pk[3] = (f16)u.w;
                pk[4] = (f16)v.x; pk[5] = (f16)v.y; pk[6] = (f16)v.z; pk[7] = (f16)v.w;
            }
            tb[ml * 97 + ch] = pk;
        }
        __syncthreads();
        const size_t tbase = (size_t)(m0 >> 7) * TILE_ELEMS + (size_t)(m0 & 127) * 8;
#pragma unroll
        for (int i = 0; i < 6; ++i) {
            const int idx = tid + 256 * i;
            const int ch2 = idx >> 4;
            const int m2 = idx & 15;
            *(f16x8*)(A + tbase + (size_t)ch2 * 1024 + (size_t)m2 * 8) = tb[m2 * 97 + ch2];
        }
    } else {  // -------- conv_b: 16 rows x 96 ch ------
        const int n0 = (blockIdx.x - CA_BLOCKS) * 16;
#pragma unroll
        for (int i = 0; i < 6; ++i) {
            const int idx = tid + 256 * i;
            const int nl = idx / 96;
            const int ch = idx - nl * 96;
            const int n = n0 + nl;
            const int c0 = ch * 8;
            f16x8 pk = (f16x8)(f16)0.f;
            const float* src = nullptr;
            if (n < 4096) {
                src = (c0 < ND) ? Wih + (size_t)n * ND + c0 : Whh + (size_t)n * NH + (c0 - ND);
            } else {
                const int c = n - 4096;
                if (c < 64 && c0 >= ND) src = Wt + (size_t)c * NH + (c0 - ND);
            }
            if (src) {
                const float4 u = ((const float4*)src)[0];
                const float4 v = ((const float4*)src)[1];
                pk[0] = (f16)u.x; pk[1] = (f16)u.y; pk[2] = (f16)u.z; pk[3] = (f16)u.w;
                pk[4] = (f16)v.x; pk[5] = (f16)v.y; pk[6] = (f16)v.z; pk[7] = (f16)v.w;
            }
            tb[nl * 97 + ch] = pk;
        }
        if (tid < 16) {
            const int n = n0 + tid;
            biasc[n] = (n < 4096) ? bih[n] + bhh[n] : ((n - 4096) < 64 ? btv[n - 4096] : 0.f);
        }
        __syncthreads();
        const size_t tbase = (size_t)(n0 >> 7) * TILE_ELEMS + (size_t)(n0 & 127) * 8;
#pragma unroll
        for (int i = 0; i < 6; ++i) {
            const int idx = tid + 256 * i;
            const int ch2 = idx >> 4;
            const int m2 = idx & 15;
            *(f16x8*)(Bm + tbase + (size_t)ch2 * 1024 + (size_t)m2 * 8) = tb[m2 * 97 + ch2];
        }
    }
}

// -------- emission MLP + gaussian lp (fat kernel, own register budget) --------
__global__ __launch_bounds__(256) void emission_kernel(
    const float* __restrict__ h, const float* __restrict__ y,
    const float* __restrict__ W1, const float* __restrict__ b1,
    const float* __restrict__ W2, const float* __restrict__ b2,
    const float* __restrict__ W3, const float* __restrict__ b3,
    float* __restrict__ out) {
    __shared__ __align__(16) float smem[11904];
    const int tid = threadIdx.x;
    float* ssh = smem;           // 16*512
    float* W2sh = smem + 8192;   // 64*33
    float* h1sh = smem + 10304;  // 16*32
    float* h2sh = smem + 10816;  // 16*64
    float* red = smem + 11840;   // 16*4
    const int wv = tid >> 6;
    const int o = tid >> 3, seg = tid & 7;
    const int p0 = blockIdx.x * 16;
    float4 w1r[16], w3r[16];
    {
        const float4* w1p = (const float4*)(W1 + (size_t)o * NH + seg * 64);
#pragma unroll
        for (int j = 0; j < 16; ++j) w1r[j] = w1p[(j + seg * 2) & 15];  // staggered
        const float4* w3p = (const float4*)(W3 + (size_t)tid * 64);
#pragma unroll
        for (int j = 0; j < 16; ++j) w3r[j] = w3p[j];
    }
    if (tid < 64) {
        for (int j = 0; j < 32; ++j) W2sh[tid * 33 + j] = W2[tid * 32 + j];
    }
    float yv[16];
#pragma unroll
    for (int pp = 0; pp < 16; ++pp) yv[pp] = y[(size_t)(p0 + pp) * ND + tid];
    const float b1r = b1[o];
    const float b2r = b2[tid & 63];
    const float b3r = b3[tid];
#pragma unroll
    for (int pp = 0; pp < 16; ++pp) {
        const float2 hv = ((const float2*)(h + (size_t)(p0 + pp) * NH))[tid];
        ssh[pp * 512 + tid * 2] = hv.x;
        ssh[pp * 512 + tid * 2 + 1] = hv.y;
    }
    __syncthreads();
#pragma unroll
    for (int pp = 0; pp < 16; ++pp) {
        const float4* s4 = (const float4*)&ssh[pp * 512 + seg * 64];
        float p = 0.f;
#pragma unroll
        for (int it = 0; it < 16; ++it) {
            const float4 sv = s4[(it + seg * 2) & 15];  // dynamic LDS idx ok
            const float4 w = w1r[it];                   // static reg idx
            p += w.x * sv.x + w.y * sv.y + w.z * sv.z + w.w * sv.w;
        }
        p += __shfl_xor(p, 1, 64);
        p += __shfl_xor(p, 2, 64);
        p += __shfl_xor(p, 4, 64);
        if (seg == 0) h1sh[pp * 32 + o] = fmaxf(p + b1r, 0.f);
    }
    __syncthreads();
    {
        const int o2 = tid & 63;
#pragma unroll
        for (int it = 0; it < 4; ++it) {
            const int pp = wv * 4 + it;
            float s = b2r;
#pragma unroll
            for (int j = 0; j < 32; ++j) s += W2sh[o2 * 33 + j] * h1sh[pp * 32 + j];
            h2sh[pp * 64 + o2] = fmaxf(s, 0.f);
        }
    }
    __syncthreads();
#pragma unroll
    for (int pp = 0; pp < 16; ++pp) {
        float s = b3r;
        const float4* h24 = (const float4*)&h2sh[pp * 64];
#pragma unroll
        for (int j = 0; j < 16; ++j) {
            const float4 w = w3r[j], hb = h24[j];
            s += w.x * hb.x + w.y * hb.y + w.z * hb.z + w.w * hb.w;
        }
        const float d = yv[pp] - s;
        float sq = d * d;
#pragma unroll
        for (int off = 32; off > 0; off >>= 1) sq += __shfl_xor(sq, off, 64);
        if ((tid & 63) == 0) red[pp * 4 + wv] = sq;
    }
    __syncthreads();
    if (tid < 16) {
        out[OFF_Y + p0 + tid] =
            CY_CONST - 5000.f * (red[tid * 4] + red[tid * 4 + 1] + red[tid * 4 + 2] +
                                 red[tid * 4 + 3]);
    }
}

// ------- big GEMM (32x32x16 MFMA, R6-exact K-loop, R12 tm-major order) ---------
// FROZEN at the measured-best config. Failed alternates: LDS-dbuf (R5),
// fixed-B (R7), reg-prefetch (R8), atomic epilogue (R9), 108-VGPR strip (R10),
// 256x256 counted-vmcnt pipeline (R11: 273us), tn-major remap (R13).
// Structure-bound at the m97 barrier-drain ceiling (~620 TF @ K=768).
__global__ __launch_bounds__(256) void gemm_kernel(const f16* __restrict__ A,
                                                   const f16* __restrict__ Bm,
                                                   const float* __restrict__ biasc,
                                                   const float* __restrict__ sampled_h,
                                                   float* __restrict__ sq_part,
                                                   float* __restrict__ Ps) {
    __shared__ __align__(16) f16 Ash[8 * 128 * 8];
    __shared__ __align__(16) f16 Bsh[8 * 128 * 8];
    const int tid = threadIdx.x;
    const int lane = tid & 63;
    const int wave = tid >> 6;
    const int xcd = blockIdx.x & 7;
    const int slot = blockIdx.x >> 3;  // 0..527
    const int tm = xcd * 16 + slot / NTN;
    const int tn = slot % NTN;
    const int m0 = tm * 128, n0 = tn * 128;
    const int l31 = lane & 31, hk = lane >> 5;

    f32x16 acc[4];
#pragma unroll
    for (int a = 0; a < 4; ++a) acc[a] = (f32x16)0.f;

    for (int kk = 0; kk < RDIM; kk += 64) {
        __syncthreads();
        const size_t abase = (size_t)tm * TILE_ELEMS + (size_t)kk * 128;
        const size_t bbase = (size_t)tn * TILE_ELEMS + (size_t)kk * 128;
#pragma unroll
        for (int inst = 0; inst < 4; ++inst) {
            const int fb = inst * 256 + wave * 64;  // wave-uniform
            const f16* ga = A + abase + (size_t)(fb + lane) * 8;  // contiguous 1KB/inst
            const f16* gb = Bm + bbase + (size_t)(fb + lane) * 8;
            __builtin_amdgcn_global_load_lds(
                (const __attribute__((address_space(1))) void*)ga,
                (__attribute__((address_space(3))) void*)&Ash[fb * 8], 16, 0, 0);
            __builtin_amdgcn_global_load_lds(
                (const __attribute__((address_space(1))) void*)gb,
                (__attribute__((address_space(3))) void*)&Bsh[fb * 8], 16, 0, 0);
        }
        __syncthreads();
#pragma unroll
        for (int kc = 0; kc < 4; ++kc) {
            const int ch = kc * 2 + hk;
            const f16x8 af = *(const f16x8*)&Ash[(ch * 128 + wave * 32 + l31) * 8];
            f16x8 bfr[4];
#pragma unroll
            for (int ni = 0; ni < 4; ++ni)
                bfr[ni] = *(const f16x8*)&Bsh[(ch * 128 + ni * 32 + l31) * 8];
#pragma unroll
            for (int ni = 0; ni < 4; ++ni)
                acc[ni] = __builtin_amdgcn_mfma_f32_32x32x16_f16(af, bfr[ni], acc[ni], 0, 0, 0);
        }
    }

    // epilogue: C layout col=lane&31, row=(reg&3)+8*(reg>>2)+4*(lane>>5)
    if (tn == 32) {  // ---- trans: tanh + column log-softmax over i (c = i*8+j)
        const float bt0 = biasc[4096 + l31];
        const float bt1 = biasc[4096 + 32 + l31];
#pragma unroll
        for (int r = 0; r < 16; ++r) {
            const int mg = m0 + wave * 32 + (r & 3) + 8 * (r >> 2) + 4 * hk;
            if (mg < M_REAL) {
                const float v0 = ftanh(acc[0][r] + bt0);  // c = l31   (i = 0..3)
                const float v1 = ftanh(acc[1][r] + bt1);  // c = 32+l31 (i = 4..7)
                float M = fmaxf(v0, v1);
                M = fmaxf(M, __shfl_xor(M, 8, 64));
                M = fmaxf(M, __shfl_xor(M, 16, 64));
                float s = fexp2((v0 - M) * LOG2E) + fexp2((v1 - M) * LOG2E);
                s += __shfl_xor(s, 8, 64);
                s += __shfl_xor(s, 16, 64);
                const float lse = M + LN2 * flog2(s);
                const int b = mg / 511, t = mg - b * 511;
                const size_t base = (size_t)(b * NT + t + 1) * 64;
                Ps[base + l31] = v0 - lse;
                Ps[base + 32 + l31] = v1 - lse;
            }
        }
    } else {  // ---- sq epilogue: full-width rows per wave -> one slot, shfl only
        const int k0 = n0 >> 9;
        const int slot4 = (n0 >> 7) & 3;
        const float b0 = biasc[n0 + l31];
        const float b1v = biasc[n0 + 32 + l31];
        const float b2v = biasc[n0 + 64 + l31];
        const float b3v = biasc[n0 + 96 + l31];
#pragma unroll
        for (int r = 0; r < 16; ++r) {
            const int mg = m0 + wave * 32 + (r & 3) + 8 * (r >> 2) + 4 * hk;
            if (mg < M_REAL) {
                const int bb = mg / 511;
                const int tt = mg - bb * 511;
                const float* tgt = sampled_h + (size_t)((bb << 9) + tt + 1) * NH;
                const float d0 = tgt[(n0 + l31) & 511] - ftanh(acc[0][r] + b0);
                const float d1 = tgt[(n0 + 32 + l31) & 511] - ftanh(acc[1][r] + b1v);
                const float d2 = tgt[(n0 + 64 + l31) & 511] - ftanh(acc[2][r] + b2v);
                const float d3 = tgt[(n0 + 96 + l31) & 511] - ftanh(acc[3][r] + b3v);
                float rs = d0 * d0 + d1 * d1 + d2 * d2 + d3 * d3;
                rs += __shfl_xor(rs, 1, 64);
                rs += __shfl_xor(rs, 2, 64);
                rs += __shfl_xor(rs, 4, 64);
                rs += __shfl_xor(rs, 8, 64);
                rs += __shfl_xor(rs, 16, 64);
                if (l31 == 0) sq_part[(size_t)(mg * 8 + k0) * 4 + slot4] = rs;
            }
        }
    }
}

// ------ post: finalize_h + s0 + pinit ----
__global__ void post_kernel(const float* __restrict__ sq_part,
                            const float* __restrict__ initials, float* __restrict__ out) {
    const int g = blockIdx.x * 256 + threadIdx.x;  // < 131072
    const int b = g >> 12;
    const int t = (g >> 3) & 511;
    const int k = g & 7;
    float val;
    if (t == 0) {
        val = CH_CONST;
    } else {
        const int m = b * 511 + (t - 1);
        const float4 a = *(const float4*)&sq_part[(size_t)(m * 8 + k) * 4];
        val = CH_CONST - 5000.f * (a.x + a.y + a.z + a.w);
    }
    out[OFF_H + g] = val;
    if (g < 2048) {
        const int sb = g >> 6, c = g & 63;
        out[OFF_S + (size_t)sb * NT * 64 + c] = ((c >> 3) == (c & 7)) ? 1.f : 0.f;
    }
    if (g < 256) {
        float z[8];
#pragma unroll
        for (int j = 0; j < 8; ++j) z[j] = initials[j];
        out[OFF_PI + g] = z[g & 7] - lse8v(z);
    }
}

// ================= R14: chunked parallel scans ================================
// a'[i] = E_t[i] + lse_j(a[j] + T_t[i][j]) is an associative affine-lse map.
// 511 steps -> 16 chunks of 32. Phase 1 (scan_mat): basis runs -> 8x8 chunk
// transfer matrices. Phase 2 (scan_fin): prefix-compose then re-run writing.
// Serial depth 511 -> ~80; parallelism 8 waves -> 1024 waves. (R14: -62us)

template <bool WRITE>
__device__ __forceinline__ float fwd_run(const float* __restrict__ Ps,
                                         const float* __restrict__ Ph,
                                         const float* __restrict__ Py,
                                         float* __restrict__ Fw, int b, int t0,
                                         int t1, float a, int lane) {
    const int i = lane & 7;
    const int base = lane & ~7;
    float4 cA[8], cB[8], nA[8], nB[8];
    float cH[8], cY[8], nH[8], nY[8];
#define FLOADR(G, A_, B_, H_, Y_)                                              \
    _Pragma("unroll") for (int jj = 0; jj < 8; ++jj) {                         \
        int t = t0 + (G) * 8 + jj;                                             \
        t = t > t1 ? t1 : t;                                                   \
        const size_t p = (size_t)(b * NT + t) * 64 + i * 8;                    \
        A_[jj] = *(const float4*)&Ps[p];                                       \
        B_[jj] = *(const float4*)&Ps[p + 4];                                   \
        H_[jj] = Ph[(size_t)(b * NT + t) * 8 + i];                             \
        Y_[jj] = Py[b * NT + t];                                               \
    }
#define FSTEPR(G, A_, B_, H_, Y_)                                              \
    _Pragma("unroll") for (int jj = 0; jj < 8; ++jj) {                         \
        const int t = t0 + (G) * 8 + jj;                                       \
        if (t <= t1) {                                                         \
            float z[8];                                                        \
            z[0] = __shfl(a, base + 0, 64) + A_[jj].x;                         \
            z[1] = __shfl(a, base + 1, 64) + A_[jj].y;                         \
            z[2] = __shfl(a, base + 2, 64) + A_[jj].z;                         \
            z[3] = __shfl(a, base + 3, 64) + A_[jj].w;                         \
            z[4] = __shfl(a, base + 4, 64) + B_[jj].x;                         \
            z[5] = __shfl(a, base + 5, 64) + B_[jj].y;                         \
            z[6] = __shfl(a, base + 6, 64) + B_[jj].z;                         \
            z[7] = __shfl(a, base + 7, 64) + B_[jj].w;                         \
            a = (H_[jj] + Y_[jj]) + lse8v(z);                                  \
            if (WRITE && lane < 8) Fw[(size_t)(b * NT + t) * 8 + i] = a;       \
        }                                                                      \
    }
    FLOADR(0, cA, cB, cH, cY);
    FLOADR(1, nA, nB, nH, nY);
    FSTEPR(0, cA, cB, cH, cY);
    FLOADR(2, cA, cB, cH, cY);
    FSTEPR(1, nA, nB, nH, nY);
    FLOADR(3, nA, nB, nH, nY);
    FSTEPR(2, cA, cB, cH, cY);
    FSTEPR(3, nA, nB, nH, nY);
#undef FLOADR
#undef FSTEPR
    return a;
}

template <bool WRITE>
__device__ __forceinline__ float bwd_run(const float* __restrict__ Ps,
                                         const float* __restrict__ Ph,
                                         const float* __restrict__ Py,
                                         float* __restrict__ Bw, int b, int tt0,
                                         int tt1, float a, int lane) {
    const int i = lane & 7;
    const int base = lane & ~7;
    float cS[8][8], nS[8][8], cH[8], cY[8], nH[8], nY[8];
#define BLOADR(G, S_, H_, Y_)                                                  \
    _Pragma("unroll") for (int jj = 0; jj < 8; ++jj) {                         \
        int t = tt0 - (G) * 8 - jj;                                            \
        t = t < tt1 ? tt1 : t;                                                 \
        const size_t q = (size_t)(b * NT + t + 1);                             \
        _Pragma("unroll") for (int ii = 0; ii < 8; ++ii)                       \
            S_[jj][ii] = Ps[q * 64 + ii * 8 + i];                              \
        H_[jj] = Ph[q * 8 + i];                                                \
        Y_[jj] = Py[q];                                                       \
    }
#define BSTEPR(G, S_, H_, Y_)                                                  \
    _Pragma("unroll") for (int jj = 0; jj < 8; ++jj) {                         \
        const int t = tt0 - (G) * 8 - jj;                                      \
        if (t >= tt1) {                                                        \
            const float v = H_[jj] + Y_[jj] + a;                               \
            float z[8];                                                        \
            _Pragma("unroll") for (int ii = 0; ii < 8; ++ii)                   \
                z[ii] = __shfl(v, base + ii, 64) + S_[jj][ii];                 \
            a = lse8v(z);                                                      \
            if (WRITE && lane < 8) Bw[(size_t)(b * NT + t) * 8 + i] = a;       \
        }                                                                      \
    }
    BLOADR(0, cS, cH, cY);
    BLOADR(1, nS, nH, nY);
    BSTEPR(0, cS, cH, cY);
    BLOADR(2, cS, cH, cY);
    BSTEPR(1, nS, nH, nY);
    BLOADR(3, nS, nH, nY);
    BSTEPR(2, cS, cH, cY);
    BSTEPR(3, nS, nH, nY);
#undef BLOADR
#undef BSTEPR
    return a;
}

// phase 1: basis runs -> chunk transfer matrices.
// blocks 0..127 fwd (b = blk>>2, c = (blk&3)*4+wave); 128..255 bwd.
__global__ __launch_bounds__(256) void scan_mat_kernel(const float* __restrict__ out,
                                                       float* __restrict__ Mws) {
    const float* Ps = out + OFF_S;
    const float* Ph = out + OFF_H;
    const float* Py = out + OFF_Y;
    const int lane = threadIdx.x & 63;
    const int wave = threadIdx.x >> 6;
    const int i = lane & 7, j = lane >> 3;
    float a = (i == j) ? 0.f : NEGINF;
    if (blockIdx.x < 128) {
        const int b = blockIdx.x >> 2;
        const int c = (blockIdx.x & 3) * 4 + wave;
        const int t0 = 1 + 32 * c;
        const int t1 = (32 * (c + 1) < 511) ? 32 * (c + 1) : 511;
        a = fwd_run<false>(Ps, Ph, Py, nullptr, b, t0, t1, a, lane);
        Mws[(size_t)(b * 16 + c) * 64 + lane] = a;
    } else {
        const int b = (blockIdx.x - 128) >> 2;
        const int c = ((blockIdx.x - 128) & 3) * 4 + wave;
        const int tt0 = 510 - 32 * c;
        const int tt1 = (479 - 32 * c > 0) ? 479 - 32 * c : 0;
        a = bwd_run<false>(Ps, Ph, Py, nullptr, b, tt0, tt1, a, lane);
        Mws[32768 + (size_t)(b * 16 + c) * 64 + lane] = a;
    }
}

// phase 2: prefix-compose (pipelined row loads) then re-run chunk writing out.
__global__ __launch_bounds__(256) void scan_fin_kernel(const float* __restrict__ initials,
                                                       float* __restrict__ out,
                                                       const float* __restrict__ Mws) {
    const float* Ps = out + OFF_S;
    const float* Ph = out + OFF_H;
    const float* Py = out + OFF_Y;
    const int lane = threadIdx.x & 63;
    const int wave = threadIdx.x >> 6;
    const int i = lane & 7;
    const int base = lane & ~7;
    const bool fwd = blockIdx.x < 128;
    const int blk = fwd ? blockIdx.x : blockIdx.x - 128;
    const int b = blk >> 2;
    const int c = (blk & 3) * 4 + wave;
    const float* Mbase = Mws + (fwd ? 0 : 32768) + (size_t)(b * 16) * 64;

    float a;
    if (fwd) {
        float z0[8];
#pragma unroll
        for (int jj = 0; jj < 8; ++jj) z0[jj] = initials[jj];
        a = (z0[i] - lse8v(z0)) + CH_CONST + Py[b * NT];
        if (c == 0 && lane < 8) (out + OFF_F)[(size_t)(b * NT) * 8 + i] = a;
    } else {
        a = 0.f;
        if (c == 0 && lane < 8) (out + OFF_BW)[(size_t)(b * NT + NT - 1) * 8 + i] = 0.f;
    }
    // prefix: apply chunks 0..c-1 (software-pipelined row loads)
    if (c > 0) {
        float4 r0 = *(const float4*)&Mbase[0 * 64 + i * 8];
        float4 r1 = *(const float4*)&Mbase[0 * 64 + i * 8 + 4];
        for (int cc = 0; cc < c; ++cc) {
            float4 s0, s1;
            if (cc + 1 < c) {
                s0 = *(const float4*)&Mbase[(size_t)(cc + 1) * 64 + i * 8];
                s1 = *(const float4*)&Mbase[(size_t)(cc + 1) * 64 + i * 8 + 4];
            }
            float z[8];
            z[0] = __shfl(a, base + 0, 64) + r0.x;
            z[1] = __shfl(a, base + 1, 64) + r0.y;
            z[2] = __shfl(a, base + 2, 64) + r0.z;
            z[3] = __shfl(a, base + 3, 64) + r0.w;
            z[4] = __shfl(a, base + 4, 64) + r1.x;
            z[5] = __shfl(a, base + 5, 64) + r1.y;
            z[6] = __shfl(a, base + 6, 64) + r1.z;
            z[7] = __shfl(a, base + 7, 64) + r1.w;
            a = lse8v(z);
            r0 = s0;
            r1 = s1;
        }
    }
    if (fwd) {
        const int t0 = 1 + 32 * c;
        const int t1 = (32 * (c + 1) < 511) ? 32 * (c + 1) : 511;
        fwd_run<true>(Ps, Ph, Py, out + OFF_F, b, t0, t1, a, lane);
    } else {
        const int tt0 = 510 - 32 * c;
        const int tt1 = (479 - 32 * c > 0) ? 479 - 32 * c : 0;
        bwd_run<true>(Ps, Ph, Py, out + OFF_BW, b, tt0, tt1, a, lane);
    }
}

// ---------------- fused gamma2 (511 blocks) + gamma1 (64 blocks) ---------------
__global__ void gamma_kernel(float* __restrict__ out) {
    const float* Ps = out + OFF_S;
    const float* Ph = out + OFF_H;
    const float* Py = out + OFF_Y;
    const float* Fw = out + OFF_F;
    const float* Bw = out + OFF_BW;
    if (blockIdx.x < 511) {
        const int gidx = blockIdx.x * 256 + threadIdx.x;  // < 130816 = 32*511*8
        const int pos = gidx >> 3;                        // b*511 + t
        const int i = gidx & 7;
        const int b = pos / 511, t = pos - b * 511;
        const size_t t1 = (size_t)(b * NT + t + 1);
        const float ei = Ph[t1 * 8 + i] + Py[t1] + Bw[t1 * 8 + i];
        const float4 sa = ((const float4*)&Ps[(t1 * 8 + i) * 8])[0];
        const float4 sb = ((const float4*)&Ps[(t1 * 8 + i) * 8])[1];
        const float4 fa = ((const float4*)&Fw[(size_t)(b * NT + t) * 8])[0];
        const float4 fb = ((const float4*)&Fw[(size_t)(b * NT + t) * 8])[1];
        float z[8] = {fa.x + sa.x + ei, fa.y + sa.y + ei, fa.z + sa.z + ei, fa.w + sa.w + ei,
                      fb.x + sb.x + ei, fb.y + sb.y + ei, fb.z + sb.z + ei, fb.w + sb.w + ei};
        float M = fmaxf(fmaxf(fmaxf(z[0], z[1]), fmaxf(z[2], z[3])),
                        fmaxf(fmaxf(z[4], z[5]), fmaxf(z[6], z[7])));
        M = fmaxf(M, __shfl_xor(M, 1, 64));
        M = fmaxf(M, __shfl_xor(M, 2, 64));
        M = fmaxf(M, __shfl_xor(M, 4, 64));
        float s = 0.f;
#pragma unroll
        for (int j = 0; j < 8; ++j) s += fexp2((z[j] - M) * LOG2E);
        s += __shfl_xor(s, 1, 64);
        s += __shfl_xor(s, 2, 64);
        s += __shfl_xor(s, 4, 64);
        const float l = M + LN2 * flog2(s);
        float* G2 = out + OFF_G2;
        float4 o0 = {z[0] - l, z[1] - l, z[2] - l, z[3] - l};
        float4 o1 = {z[4] - l, z[5] - l, z[6] - l, z[7] - l};
        ((float4*)&G2[(size_t)gidx * 8])[0] = o0;
        ((float4*)&G2[(size_t)gidx * 8])[1] = o1;
    } else {
        const int pos = (blockIdx.x - 511) * 256 + threadIdx.x;  // < 16384
        const float4 fa = ((const float4*)&Fw[(size_t)pos * 8])[0];
        const float4 fb = ((const float4*)&Fw[(size_t)pos * 8])[1];
        const float4 ba = ((const float4*)&Bw[(size_t)pos * 8])[0];
        const float4 bb = ((const float4*)&Bw[(size_t)pos * 8])[1];
        float ab[8] = {fa.x + ba.x, fa.y + ba.y, fa.z + ba.z, fa.w + ba.w,
                       fb.x + bb.x, fb.y + bb.y, fb.z + bb.z, fb.w + bb.w};
        const float l = lse8v(ab);
        float* G1 = out + OFF_G1;
        float4 o0 = {ab[0] - l, ab[1] - l, ab[2] - l, ab[3] - l};
        float4 o1 = {ab[4] - l, ab[5] - l, ab[6] - l, ab[7] - l};
        ((float4*)&G1[(size_t)pos * 8])[0] = o0;
        ((float4*)&G1[(size_t)pos * 8])[1] = o1;
    }
}

extern "C" void kernel_launch(void* const* d_in, const int* in_sizes, int n_in, void* d_out,
                              int out_size, void* d_ws, size_t ws_size, hipStream_t stream) {
    const float* x = (const float*)d_in[0];
    const float* y = (const float*)d_in[1];
    const float* h = (const float*)d_in[2];
    const float* initials = (const float*)d_in[3];
    const float* Wih = (const float*)d_in[4];
    const float* Whh = (const float*)d_in[5];
    const float* bih = (const float*)d_in[6];
    const float* bhh = (const float*)d_in[7];
    const float* Wt = (const float*)d_in[8];
    const float* btv = (const float*)d_in[9];
    const float* W1 = (const float*)d_in[10];
    const float* b1 = (const float*)d_in[11];
    const float* W2 = (const float*)d_in[12];
    const float* b2 = (const float*)d_in[13];
    const float* W3 = (const float*)d_in[14];
    const float* b3 = (const float*)d_in[15];
    float* out = (float*)d_out;
    char* ws = (char*)d_ws;
    if (ws_size < (size_t)WS_NEED) return;
    f16* Aws = (f16*)(ws + WS_A);
    f16* Bws = (f16*)(ws + WS_B);
    float* biasc = (float*)(ws + WS_BIAS);
    float* sqp = (float*)(ws + WS_SQ);
    float* Mws = (float*)(ws + WS_M);

    conv_ab_kernel<<<CONV_GRID, 256, 0, stream>>>(x, h, Wih, Whh, bih, bhh, Wt, btv, Aws,
                                                  Bws, biasc);
    gemm_kernel<<<4224, 256, 0, stream>>>(Aws, Bws, biasc, h, sqp, out + OFF_S);
    emission_kernel<<<1024, 256, 0, stream>>>(h, y, W1, b1, W2, b2, W3, b3, out);
    post_kernel<<<512, 256, 0, stream>>>(sqp, initials, out);
    scan_mat_kernel<<<256, 256, 0, stream>>>(out, Mws);
    scan_fin_kernel<<<256, 256, 0, stream>>>(initials, out, Mws);
    gamma_kernel<<<575, 256, 0, stream>>>(out);
}